// Round 1
// baseline (1133.002 us; speedup 1.0000x reference)
//
#include <hip/hip_runtime.h>
#include <math.h>

#define BS 16
#define SEQ 512
#define VOCAB 32000
#define NMASK 80
#define NITEM (BS * NMASK)   // 1280

// ---------------------------------------------------------------------------
// Kernel A: per row, find the NMASK masked positions in ascending order.
// One block of 64 threads per row; ballot + popcount prefix rank.
// ---------------------------------------------------------------------------
__global__ void find_pos_kernel(const int* __restrict__ mask, int* __restrict__ pos) {
    int b = blockIdx.x;
    int lane = threadIdx.x;  // 0..63
    int base = 0;
    for (int i = 0; i < SEQ / 64; ++i) {
        int s = i * 64 + lane;
        int m = mask[b * SEQ + s];
        unsigned long long bal = __ballot(m != 0);
        int rank = base + __popcll(bal & ((1ull << lane) - 1ull));
        if (m != 0) pos[b * NMASK + rank] = s;   // exactly NMASK set per row
        base += __popcll(bal);
    }
}

// ---------------------------------------------------------------------------
// Kernel B: one block per (b, j) item. Vectorized float4 scan of the 32000-
// entry vocab row: argmax (first-occurrence tiebreak) + gather logp at target.
// ---------------------------------------------------------------------------
__global__ __launch_bounds__(256) void row_argmax_kernel(
        const float* __restrict__ out, const int* __restrict__ target,
        const int* __restrict__ pos, float* __restrict__ logp,
        int* __restrict__ correct) {
    int bj = blockIdx.x;               // 0..1279
    int b  = bj / NMASK;
    int p  = pos[bj];
    const float* row = out + ((size_t)b * SEQ + (size_t)p) * VOCAB;
    const float4* row4 = reinterpret_cast<const float4*>(row);

    float bv = -INFINITY;
    int   bi = 0;
    // VOCAB/4 = 8000 float4s, 256 threads -> 31-32 iters each; indices
    // increase within a thread so strict '>' keeps first occurrence.
    for (int i = threadIdx.x; i < VOCAB / 4; i += 256) {
        float4 v = row4[i];
        int base = i * 4;
        if (v.x > bv) { bv = v.x; bi = base;     }
        if (v.y > bv) { bv = v.y; bi = base + 1; }
        if (v.z > bv) { bv = v.z; bi = base + 2; }
        if (v.w > bv) { bv = v.w; bi = base + 3; }
    }

    // wave64 shuffle reduce (prefer smaller index on ties)
    for (int off = 32; off > 0; off >>= 1) {
        float ov = __shfl_down(bv, off);
        int   oi = __shfl_down(bi, off);
        if (ov > bv || (ov == bv && oi < bi)) { bv = ov; bi = oi; }
    }

    __shared__ float sv[4];
    __shared__ int   si[4];
    int wave = threadIdx.x >> 6;
    int lane = threadIdx.x & 63;
    if (lane == 0) { sv[wave] = bv; si[wave] = bi; }
    __syncthreads();

    if (threadIdx.x == 0) {
        float fv = sv[0]; int fi = si[0];
        for (int w = 1; w < 4; ++w) {
            if (sv[w] > fv || (sv[w] == fv && si[w] < fi)) { fv = sv[w]; fi = si[w]; }
        }
        int t = target[bj];
        logp[bj]    = row[t];
        correct[bj] = (fi == t) ? 1 : 0;
    }
}

// ---------------------------------------------------------------------------
// Kernel C: deterministic finalize. fp64 tree-sum of logp + int count.
// avg_loss = -sum(logp)/1280 ; acc = correct/1280
// ---------------------------------------------------------------------------
__global__ void finalize_kernel(const float* __restrict__ logp,
                                const int* __restrict__ correct,
                                float* __restrict__ out) {
    __shared__ double ssum[256];
    __shared__ int    scnt[256];
    double s = 0.0;
    int    c = 0;
    for (int i = threadIdx.x; i < NITEM; i += 256) {
        s += (double)logp[i];
        c += correct[i];
    }
    ssum[threadIdx.x] = s;
    scnt[threadIdx.x] = c;
    __syncthreads();
    for (int off = 128; off > 0; off >>= 1) {
        if (threadIdx.x < off) {
            ssum[threadIdx.x] += ssum[threadIdx.x + off];
            scnt[threadIdx.x] += scnt[threadIdx.x + off];
        }
        __syncthreads();
    }
    if (threadIdx.x == 0) {
        out[0] = (float)(-ssum[0] / (double)NITEM);
        out[1] = (float)((double)scnt[0] / (double)NITEM);
    }
}

extern "C" void kernel_launch(void* const* d_in, const int* in_sizes, int n_in,
                              void* d_out, int out_size, void* d_ws, size_t ws_size,
                              hipStream_t stream) {
    const float* output = (const float*)d_in[0];   // (16, 512, 32000) f32
    const int*   target = (const int*)d_in[1];     // (16, 80) int
    const int*   mask   = (const int*)d_in[2];     // (16, 512) int (0/1)
    float* out = (float*)d_out;                    // [avg_loss, acc]

    int*   ws_pos     = (int*)d_ws;                       // NITEM ints
    float* ws_logp    = (float*)((char*)d_ws + NITEM * sizeof(int));
    int*   ws_correct = (int*)((char*)d_ws + 2 * NITEM * sizeof(int));

    find_pos_kernel<<<BS, 64, 0, stream>>>(mask, ws_pos);
    row_argmax_kernel<<<NITEM, 256, 0, stream>>>(output, target, ws_pos,
                                                 ws_logp, ws_correct);
    finalize_kernel<<<1, 256, 0, stream>>>(ws_logp, ws_correct, out);
}